// Round 4
// baseline (118.303 us; speedup 1.0000x reference)
//
#include <hip/hip_runtime.h>
#include <hip/hip_bf16.h>

// DynamicMaskHead: N=2, C=8, H=128, W=192, n_inst=128, factor=2
#define NUM_INST 128
#define H_ 128
#define W_ 192
#define HW_ (H_ * W_)      // 24576
#define OH_ 256
#define OW_ 384
#define NPAR 169           // 80 + 64 + 8 + 8 + 8 + 1

typedef float v2f __attribute__((ext_vector_type(2)));

static __device__ __forceinline__ float bf2f(unsigned short u) {
    union { unsigned int i; float f; } v;
    v.i = ((unsigned int)u) << 16;
    return v.f;
}
static __device__ __forceinline__ float hi2f(unsigned int u) {
    union { unsigned int i; float f; } v;
    v.i = u & 0xFFFF0000u;
    return v.f;
}
static __device__ __forceinline__ float lo2f(unsigned int u) {
    union { unsigned int i; float f; } v;
    v.i = u << 16;
    return v.f;
}
static __device__ __forceinline__ unsigned int f2bf(float f) {
    unsigned int u = __float_as_uint(f);
    return (u + 0x7fffu + ((u >> 16) & 1u)) >> 16;
}
static __device__ __forceinline__ v2f pkfma(v2f a, v2f b, v2f c) {
    return __builtin_elementwise_fma(a, b, c);   // -> v_pk_fma_f32
}
static __device__ __forceinline__ v2f pkrelu(v2f a) {
    const v2f z = {0.0f, 0.0f};
    return __builtin_elementwise_max(a, z);      // -> v_pk_max_f32
}

// Fused: dynamic 3-layer MLP + aligned_bilinear x2, no workspace.
// Grid (16 row-tiles, 128 instances) x 256 threads.
// R4 change: inner math on float2 ext-vectors so the compiler emits
// v_pk_fma_f32 (2 FMA/lane/instr) — the kernel is VALU-FMA-issue bound
// (608 fma instr/group x 2cyc = 1216 cyc vs LDS 540 cyc on separate pipe).
// dy-term folded into layer-0 bias (saves 8 fma/group).
__global__ __launch_bounds__(256) void fused_maskhead(
    const void* __restrict__ mf_v,    // mask_feats  (2,8,128,192)
    const void* __restrict__ par_v,   // params      (128,169)
    const void* __restrict__ loc_v,   // locations   (128,2)
    const void* __restrict__ soi_v,   // sizes       (6,)
    const int*  __restrict__ im_inds, // (128,) int32
    const int*  __restrict__ fpn,     // (128,) int32
    void*       __restrict__ out_v)   // (128,1,256,384)
{
    const int tid  = threadIdx.x;
    const int inst = blockIdx.y;
    const int r0   = blockIdx.x * 8;

    // dtype probe: sizes_of_interest[0]==64.0 -> 0x42800000 iff fp32 tensors.
    const bool f32in = (*(const unsigned int*)soi_v) == 0x42800000u;

    __shared__ __align__(16) float w0p[8][12];   // [o][0..9]=w, [10]=b0
    __shared__ __align__(16) float w1p[8][12];   // [o][0..7]=w, [8]=b1
    __shared__ __align__(16) float w2p[12];      // [0..7]=w, [8]=b2
    __shared__ __align__(16) float b1p[8];
    __shared__ float Lt[9][W_ + 2];              // stride 194 (8B-aligned rows)

    auto ldpar = [&](int k) -> float {
        return f32in ? ((const float*)par_v)[inst * NPAR + k]
                     : bf2f(((const unsigned short*)par_v)[inst * NPAR + k]);
    };

    if (tid < 96) {
        const int o = tid / 12, i = tid - o * 12;
        float v = 0.0f;
        if (i < 10) v = ldpar(o * 10 + i);
        else if (i == 10) v = ldpar(152 + o);
        w0p[o][i] = v;
    } else if (tid < 192) {
        const int t = tid - 96, o = t / 12, i = t - o * 12;
        float v = 0.0f;
        if (i < 8) v = ldpar(80 + o * 8 + i);
        else if (i == 8) v = ldpar(160 + o);
        w1p[o][i] = v;
    } else if (tid < 204) {
        const int t = tid - 192;
        float v = 0.0f;
        if (t < 8) v = ldpar(144 + t);
        else if (t == 8) v = ldpar(168);
        w2p[t] = v;
    } else if (tid < 212) {
        b1p[tid - 204] = ldpar(160 + tid - 204);
    }

    float lx, ly, soi;
    const int lvl = fpn[inst];
    if (f32in) {
        lx  = ((const float*)loc_v)[inst * 2 + 0];
        ly  = ((const float*)loc_v)[inst * 2 + 1];
        soi = ((const float*)soi_v)[lvl];
    } else {
        lx  = bf2f(((const unsigned short*)loc_v)[inst * 2 + 0]);
        ly  = bf2f(((const unsigned short*)loc_v)[inst * 2 + 1]);
        soi = bf2f(((const unsigned short*)soi_v)[lvl]);
    }
    const float invs = 1.0f / soi;
    const size_t fo  = (size_t)im_inds[inst] * 8 * HW_;

    __syncthreads();

    // ---- phase 1: 9 logit rows into LDS. 432 groups of 4 px. ----
    auto do_group = [&](int g) {
        const int j  = g / 48;               // row slot 0..8
        const int c0 = (g - j * 48) * 4;     // col 0..188 step 4
        int rr = r0 - 1 + j; if (rr < 0) rr = 0;
        const int poff = rr * W_ + c0;

        const float dy  = (ly - (float)(rr * 8 + 4)) * invs;
        const float dx0 = (lx - (float)(c0 * 8 + 4)) * invs;
        const float st  = -8.0f * invs;

        // inputs as pixel-pairs: index 0 = dx, 1..8 = feat channels
        v2f xA[9], xB[9];
        xA[0] = (v2f){dx0, dx0 + st};
        xB[0] = (v2f){dx0 + 2.0f * st, dx0 + 3.0f * st};
        if (f32in) {
            const float* fb = (const float*)mf_v + fo + poff;
#pragma unroll
            for (int ch = 0; ch < 8; ch++) {
                float4 f = *(const float4*)(fb + ch * HW_);
                xA[1 + ch] = (v2f){f.x, f.y};
                xB[1 + ch] = (v2f){f.z, f.w};
            }
        } else {
            const unsigned short* fb = (const unsigned short*)mf_v + fo + poff;
#pragma unroll
            for (int ch = 0; ch < 8; ch++) {
                uint2 f = *(const uint2*)(fb + ch * HW_);
                xA[1 + ch] = (v2f){lo2f(f.x), hi2f(f.x)};
                xB[1 + ch] = (v2f){lo2f(f.y), hi2f(f.y)};
            }
        }

        // layer 0: 10 -> 8, relu (dy folded into bias)
        v2f h1A[8], h1B[8];
#pragma unroll
        for (int o = 0; o < 8; o++) {
            const float4 qa = *(const float4*)&w0p[o][0];  // [dx, dy, f0, f1]
            const float4 qb = *(const float4*)&w0p[o][4];  // [f2..f5]
            const float4 qc = *(const float4*)&w0p[o][8];  // [f6, f7, b0, 0]
            const float wl[9] = {qa.x, qa.z, qa.w, qb.x, qb.y,
                                 qb.z, qb.w, qc.x, qc.y};
            const float t = fmaf(qa.y, dy, qc.z);
            v2f a01 = (v2f){t, t}, a23 = (v2f){t, t};
#pragma unroll
            for (int i = 0; i < 9; i++) {
                const v2f ws = (v2f){wl[i], wl[i]};
                a01 = pkfma(ws, xA[i], a01);
                a23 = pkfma(ws, xB[i], a23);
            }
            h1A[o] = pkrelu(a01);
            h1B[o] = pkrelu(a23);
        }

        // layer 1: 8 -> 8, relu
        const float4 bqa = *(const float4*)&b1p[0];
        const float4 bqb = *(const float4*)&b1p[4];
        const float b1r[8] = {bqa.x, bqa.y, bqa.z, bqa.w,
                              bqb.x, bqb.y, bqb.z, bqb.w};
        v2f h2A[8], h2B[8];
#pragma unroll
        for (int o = 0; o < 8; o++) {
            const float4 qa = *(const float4*)&w1p[o][0];
            const float4 qb = *(const float4*)&w1p[o][4];
            const float wl[8] = {qa.x, qa.y, qa.z, qa.w,
                                 qb.x, qb.y, qb.z, qb.w};
            const float b = b1r[o];
            v2f a01 = (v2f){b, b}, a23 = (v2f){b, b};
#pragma unroll
            for (int i = 0; i < 8; i++) {
                const v2f ws = (v2f){wl[i], wl[i]};
                a01 = pkfma(ws, h1A[i], a01);
                a23 = pkfma(ws, h1B[i], a23);
            }
            h2A[o] = pkrelu(a01);
            h2B[o] = pkrelu(a23);
        }

        // layer 2: 8 -> 1
        const float4 qa = *(const float4*)&w2p[0];
        const float4 qb = *(const float4*)&w2p[4];
        const float wl[8] = {qa.x, qa.y, qa.z, qa.w, qb.x, qb.y, qb.z, qb.w};
        const float b2 = w2p[8];
        v2f oA = (v2f){b2, b2}, oB = (v2f){b2, b2};
#pragma unroll
        for (int i = 0; i < 8; i++) {
            const v2f ws = (v2f){wl[i], wl[i]};
            oA = pkfma(ws, h2A[i], oA);
            oB = pkfma(ws, h2B[i], oB);
        }

        *(v2f*)&Lt[j][c0]     = oA;   // rows are 8B-aligned (stride 194)
        *(v2f*)&Lt[j][c0 + 2] = oB;
    };

    do_group(tid);                       // groups 0..255
    if (tid < 176) do_group(tid + 256);  // groups 256..431

    __syncthreads();

    // ---- phase 2: emit 2x upsampled output (1536 quads, 6 per thread) ----
    for (int q = tid; q < 1536; q += 256) {
        const int rl = q / 192;          // 0..7
        const int c  = q - rl * 192;     // 0..191
        const int r  = r0 + rl;
        const int cm = c ? c - 1 : 0;

        const float a = Lt[rl][cm],     b = Lt[rl][c];
        const float d = Lt[rl + 1][cm], e = Lt[rl + 1][c];

        const float v00 = 0.25f * (a + b + d + e);
        const float v01 = 0.5f  * (b + e);
        const float v10 = 0.5f  * (d + e);
        const float v11 = e;

        const size_t base = ((size_t)inst * OH_ + 2 * r) * (size_t)OW_ + 2 * c;
        if (f32in) {
            float* of = (float*)out_v;
            *(float2*)(of + base)       = make_float2(v00, v01);
            *(float2*)(of + base + OW_) = make_float2(v10, v11);
        } else {
            unsigned int* ob = (unsigned int*)out_v;
            ob[base >> 1]         = f2bf(v00) | (f2bf(v01) << 16);
            ob[(base + OW_) >> 1] = f2bf(v10) | (f2bf(v11) << 16);
        }
    }
}

extern "C" void kernel_launch(void* const* d_in, const int* in_sizes, int n_in,
                              void* d_out, int out_size, void* d_ws, size_t ws_size,
                              hipStream_t stream) {
    (void)in_sizes; (void)n_in; (void)d_ws; (void)ws_size; (void)out_size;
    dim3 grid(H_ / 8, NUM_INST);   // (16, 128)
    fused_maskhead<<<grid, 256, 0, stream>>>(d_in[0], d_in[1], d_in[2], d_in[3],
                                             (const int*)d_in[4],
                                             (const int*)d_in[5], d_out);
}

// Round 5
// 103.284 us; speedup vs baseline: 1.1454x; 1.1454x over previous
//
#include <hip/hip_runtime.h>
#include <hip/hip_bf16.h>

// DynamicMaskHead: N=2, C=8, H=128, W=192, n_inst=128, factor=2
#define NUM_INST 128
#define H_ 128
#define W_ 192
#define HW_ (H_ * W_)      // 24576
#define OH_ 256
#define OW_ 384
#define NPAR 169           // 80 + 64 + 8 + 8 + 8 + 1

typedef float v2f __attribute__((ext_vector_type(2)));

static __device__ __forceinline__ float bf2f(unsigned short u) {
    union { unsigned int i; float f; } v;
    v.i = ((unsigned int)u) << 16;
    return v.f;
}
static __device__ __forceinline__ float hi2f(unsigned int u) {
    union { unsigned int i; float f; } v;
    v.i = u & 0xFFFF0000u;
    return v.f;
}
static __device__ __forceinline__ float lo2f(unsigned int u) {
    union { unsigned int i; float f; } v;
    v.i = u << 16;
    return v.f;
}
static __device__ __forceinline__ unsigned int f2bf(float f) {
    unsigned int u = __float_as_uint(f);
    return (u + 0x7fffu + ((u >> 16) & 1u)) >> 16;
}
static __device__ __forceinline__ v2f pkfma(v2f a, v2f b, v2f c) {
    return __builtin_elementwise_fma(a, b, c);   // v_pk_fma_f32
}
static __device__ __forceinline__ v2f pkrelu(v2f a) {
    const v2f z = {0.0f, 0.0f};
    return __builtin_elementwise_max(a, z);
}

// K1: dynamic 3-layer MLP -> fp32 logits in workspace.
// 2 px/thread, one unit per thread (no raggedness, no halo, no output tile).
// Designed for occupancy: R4 post-mortem showed 216 VGPR -> 9.7% occupancy,
// VALUBusy 31% -> latency-bound. Cap at 128 VGPR (>=4 waves/SIMD).
__global__ __launch_bounds__(256, 4) void mlp_kernel(
    const void* __restrict__ mf_v,    // mask_feats  (2,8,128,192)
    const void* __restrict__ par_v,   // params      (128,169)
    const void* __restrict__ loc_v,   // locations   (128,2)
    const void* __restrict__ soi_v,   // sizes       (6,)
    const int*  __restrict__ im_inds, // (128,) int32
    const int*  __restrict__ fpn,     // (128,) int32
    float*      __restrict__ logits)  // (128, HW_) fp32 ws
{
    const int tid  = threadIdx.x;
    const int inst = blockIdx.y;

    // dtype probe: sizes_of_interest[0]==64.0 -> 0x42800000 iff fp32 tensors.
    const bool f32in = (*(const unsigned int*)soi_v) == 0x42800000u;

    __shared__ __align__(16) float w0p[8][12];   // [o][0..9]=w, [10]=b0
    __shared__ __align__(16) float w1p[8][12];   // [o][0..7]=w, [8]=b1
    __shared__ __align__(16) float w2p[12];      // [0..7]=w, [8]=b2
    __shared__ __align__(16) float b1p[8];

    auto ldpar = [&](int k) -> float {
        return f32in ? ((const float*)par_v)[inst * NPAR + k]
                     : bf2f(((const unsigned short*)par_v)[inst * NPAR + k]);
    };

    if (tid < 96) {
        const int o = tid / 12, i = tid - o * 12;
        float v = 0.0f;
        if (i < 10) v = ldpar(o * 10 + i);
        else if (i == 10) v = ldpar(152 + o);
        w0p[o][i] = v;
    } else if (tid < 192) {
        const int t = tid - 96, o = t / 12, i = t - o * 12;
        float v = 0.0f;
        if (i < 8) v = ldpar(80 + o * 8 + i);
        else if (i == 8) v = ldpar(160 + o);
        w1p[o][i] = v;
    } else if (tid < 204) {
        const int t = tid - 192;
        float v = 0.0f;
        if (t < 8) v = ldpar(144 + t);
        else if (t == 8) v = ldpar(168);
        w2p[t] = v;
    } else if (tid < 212) {
        b1p[tid - 204] = ldpar(160 + tid - 204);
    }

    float lx, ly, soi;
    const int lvl = fpn[inst];
    if (f32in) {
        lx  = ((const float*)loc_v)[inst * 2 + 0];
        ly  = ((const float*)loc_v)[inst * 2 + 1];
        soi = ((const float*)soi_v)[lvl];
    } else {
        lx  = bf2f(((const unsigned short*)loc_v)[inst * 2 + 0]);
        ly  = bf2f(((const unsigned short*)loc_v)[inst * 2 + 1]);
        soi = bf2f(((const unsigned short*)soi_v)[lvl]);
    }
    const float invs = 1.0f / soi;
    const size_t fo  = (size_t)im_inds[inst] * 8 * HW_;

    __syncthreads();

    const int p0 = (blockIdx.x * 256 + tid) * 2;   // 2 px, same row (192 even)
    const int r  = p0 / W_;
    const int c0 = p0 - r * W_;

    const float dy  = (ly - (float)(r * 8 + 4)) * invs;
    const float dx0 = (lx - (float)(c0 * 8 + 4)) * invs;
    const float st  = -8.0f * invs;

    v2f x[9];                         // 0 = dx pair, 1..8 = feat channels
    x[0] = (v2f){dx0, dx0 + st};
    if (f32in) {
        const float* fb = (const float*)mf_v + fo + (r * W_ + c0);
#pragma unroll
        for (int ch = 0; ch < 8; ch++) {
            float2 f = *(const float2*)(fb + ch * HW_);   // 8B aligned (p0 even)
            x[1 + ch] = (v2f){f.x, f.y};
        }
    } else {
        const unsigned short* fb = (const unsigned short*)mf_v + fo + (r * W_ + c0);
#pragma unroll
        for (int ch = 0; ch < 8; ch++) {
            unsigned int f = *(const unsigned int*)(fb + ch * HW_);
            x[1 + ch] = (v2f){lo2f(f), hi2f(f)};
        }
    }

    // layer 0: 10 -> 8, relu (dy folded into bias)
    v2f h1[8];
#pragma unroll
    for (int o = 0; o < 8; o++) {
        const float4 qa = *(const float4*)&w0p[o][0];  // [dx, dy, f0, f1]
        const float4 qb = *(const float4*)&w0p[o][4];  // [f2..f5]
        const float4 qc = *(const float4*)&w0p[o][8];  // [f6, f7, b0, 0]
        const float wl[9] = {qa.x, qa.z, qa.w, qb.x, qb.y,
                             qb.z, qb.w, qc.x, qc.y};
        const float t = fmaf(qa.y, dy, qc.z);
        v2f a = (v2f){t, t};
#pragma unroll
        for (int i = 0; i < 9; i++)
            a = pkfma((v2f){wl[i], wl[i]}, x[i], a);
        h1[o] = pkrelu(a);
    }

    // layer 1: 8 -> 8, relu
    const float4 bqa = *(const float4*)&b1p[0];
    const float4 bqb = *(const float4*)&b1p[4];
    const float b1r[8] = {bqa.x, bqa.y, bqa.z, bqa.w,
                          bqb.x, bqb.y, bqb.z, bqb.w};
    v2f h2[8];
#pragma unroll
    for (int o = 0; o < 8; o++) {
        const float4 qa = *(const float4*)&w1p[o][0];
        const float4 qb = *(const float4*)&w1p[o][4];
        const float wl[8] = {qa.x, qa.y, qa.z, qa.w, qb.x, qb.y, qb.z, qb.w};
        v2f a = (v2f){b1r[o], b1r[o]};
#pragma unroll
        for (int i = 0; i < 8; i++)
            a = pkfma((v2f){wl[i], wl[i]}, h1[i], a);
        h2[o] = pkrelu(a);
    }

    // layer 2: 8 -> 1
    const float4 qa = *(const float4*)&w2p[0];
    const float4 qb = *(const float4*)&w2p[4];
    const float wl[8] = {qa.x, qa.y, qa.z, qa.w, qb.x, qb.y, qb.z, qb.w};
    v2f o2 = (v2f){w2p[8], w2p[8]};
#pragma unroll
    for (int i = 0; i < 8; i++)
        o2 = pkfma((v2f){wl[i], wl[i]}, h2[i], o2);

    *(v2f*)(logits + (size_t)inst * HW_ + p0) = o2;
}

// K2: aligned_bilinear x2 from fp32 logits. 1 thread = 2x4 output block
// (two adjacent 2x2 quads -> float4 row stores). Pure bandwidth, tiny VGPR.
//   out[2r  ,2c  ] = 0.25*(L[r-1,c-1]+L[r-1,c]+L[r,c-1]+L[r,c])
//   out[2r  ,2c+1] = 0.5 *(L[r-1,c]+L[r,c])
//   out[2r+1,2c  ] = 0.5 *(L[r,c-1]+L[r,c])
//   out[2r+1,2c+1] =       L[r,c]        (r-1, c-1 clamped at 0)
__global__ __launch_bounds__(256) void upsample_kernel(
    const float* __restrict__ logits,  // (128, HW_)
    const void*  __restrict__ soi_v,   // dtype probe
    void*        __restrict__ out_v)   // (128,1,256,384)
{
    const bool f32in = (*(const unsigned int*)soi_v) == 0x42800000u;

    const int inst = blockIdx.y;
    const int t  = blockIdx.x * 256 + threadIdx.x;   // 0..12287
    const int r  = t / 96;
    const int cp = t - r * 96;
    const int c  = 2 * cp;                           // 0..190, even
    const int cm = c ? c - 1 : 0;
    const int rm = r ? r - 1 : 0;

    const float* L  = logits + (size_t)inst * HW_;
    const float* rU = L + rm * W_;
    const float* rD = L + r * W_;

    const float  aL = rU[cm];
    const float2 a01 = *(const float2*)(rU + c);     // 8B aligned
    const float  dL = rD[cm];
    const float2 d01 = *(const float2*)(rD + c);

    // quad at col c
    const float v00 = 0.25f * (aL + a01.x + dL + d01.x);
    const float v01 = 0.5f  * (a01.x + d01.x);
    const float v10 = 0.5f  * (dL + d01.x);
    const float v11 = d01.x;
    // quad at col c+1 (left neighbor is col c)
    const float u00 = 0.25f * (a01.x + a01.y + d01.x + d01.y);
    const float u01 = 0.5f  * (a01.y + d01.y);
    const float u10 = 0.5f  * (d01.x + d01.y);
    const float u11 = d01.y;

    const size_t base = ((size_t)inst * OH_ + 2 * r) * (size_t)OW_ + 2 * c;
    if (f32in) {
        float* of = (float*)out_v;
        *(float4*)(of + base)       = make_float4(v00, v01, u00, u01);  // 16B aligned
        *(float4*)(of + base + OW_) = make_float4(v10, v11, u10, u11);
    } else {
        unsigned int* ob = (unsigned int*)out_v;
        const size_t i0 = base >> 1;
        ob[i0]     = f2bf(v00) | (f2bf(v01) << 16);
        ob[i0 + 1] = f2bf(u00) | (f2bf(u01) << 16);
        const size_t i1 = (base + OW_) >> 1;
        ob[i1]     = f2bf(v10) | (f2bf(v11) << 16);
        ob[i1 + 1] = f2bf(u10) | (f2bf(u11) << 16);
    }
}

extern "C" void kernel_launch(void* const* d_in, const int* in_sizes, int n_in,
                              void* d_out, int out_size, void* d_ws, size_t ws_size,
                              hipStream_t stream) {
    (void)in_sizes; (void)n_in; (void)ws_size; (void)out_size;
    float* logits = (float*)d_ws;   // 12.6 MB fp32 scratch (ws is 256 MiB)

    dim3 g1(HW_ / (256 * 2), NUM_INST);   // (48, 128)
    mlp_kernel<<<g1, 256, 0, stream>>>(d_in[0], d_in[1], d_in[2], d_in[3],
                                       (const int*)d_in[4], (const int*)d_in[5],
                                       logits);

    dim3 g2((H_ * (W_ / 2)) / 256, NUM_INST);  // (48, 128)
    upsample_kernel<<<g2, 256, 0, stream>>>(logits, d_in[3], d_out);
}